// Round 14
// baseline (419.147 us; speedup 1.0000x reference)
//
#include <hip/hip_runtime.h>
#include <hip/hip_bf16.h>
#include <math.h>

#define NEG 0.2f
#define BNEPS 1e-5f
#define NGRAPH 64
#define SCAN_CHUNK 2048
#define POOL_BLOCKS 256

typedef short bf16x8 __attribute__((ext_vector_type(8)));            // 8 bf16 (4 VGPRs)
typedef float f32x4  __attribute__((ext_vector_type(4)));            // MFMA accumulator

__device__ __forceinline__ float bf2f(unsigned short u) {
    return __uint_as_float(((unsigned)u) << 16);
}
__device__ __forceinline__ short f2bf(float f) {
    return (short)__bfloat16_as_ushort(__float2bfloat16(f));
}

// ---------- MFMA bf16 GEMM for layer-0 xh: Cbf[M,256] = bf16(x @ W0) ----------
// + fused attention dots. grid (ceil(M/64), 4), block 256. head = blockIdx.y.
__global__ __launch_bounds__(256)
void gemm_xh_mfma(const float* __restrict__ A, int lda,
                  const float* __restrict__ W, int Nc, int M, int K,
                  const float* __restrict__ att_s, const float* __restrict__ att_d,
                  float* __restrict__ as_out, float* __restrict__ ad_out,
                  unsigned short* __restrict__ Cbf)
{
    __shared__ short Wt[64 * 136];           // max K=128 -> KP=136
    const int KP = K + 8;
    int tid  = threadIdx.x;
    int lane = tid & 63, wave = tid >> 6;
    int row0 = blockIdx.x * 64;
    int colb = blockIdx.y * 64;
    int c15 = lane & 15, q = lane >> 4;

    {
        int n = tid & 63;
        for (int k = tid >> 6; k < K; k += 4)
            Wt[n * KP + k] = f2bf(W[(size_t)k * Nc + colb + n]);
    }
    __syncthreads();

    int row = row0 + wave * 16 + c15;
    bool rok = row < M;
    const float* arow = A + (size_t)row * lda + q * 8;

    f32x4 acc[4];
    #pragma unroll
    for (int st = 0; st < 4; ++st) acc[st] = (f32x4){0.f, 0.f, 0.f, 0.f};

    for (int k0 = 0; k0 < K; k0 += 32) {
        bf16x8 av;
        if (rok) {
            float4 a0 = *(const float4*)(arow + k0);
            float4 a1 = *(const float4*)(arow + k0 + 4);
            av[0] = f2bf(a0.x); av[1] = f2bf(a0.y); av[2] = f2bf(a0.z); av[3] = f2bf(a0.w);
            av[4] = f2bf(a1.x); av[5] = f2bf(a1.y); av[6] = f2bf(a1.z); av[7] = f2bf(a1.w);
        } else {
            av = (bf16x8){0,0,0,0,0,0,0,0};
        }
        #pragma unroll
        for (int st = 0; st < 4; ++st) {
            bf16x8 bv = *(const bf16x8*)(Wt + (st * 16 + c15) * KP + k0 + q * 8);
            acc[st] = __builtin_amdgcn_mfma_f32_16x16x32_bf16(av, bv, acc[st], 0, 0, 0);
        }
    }

    #pragma unroll
    for (int r = 0; r < 4; ++r) {
        int orow = row0 + wave * 16 + q * 4 + r;
        if (orow >= M) continue;
        unsigned short* cb = Cbf + (size_t)orow * 256 + colb + c15;
        #pragma unroll
        for (int st = 0; st < 4; ++st)
            cb[st * 16] = (unsigned short)f2bf(acc[st][r]);
    }
    float sa[4], da[4];
    #pragma unroll
    for (int st = 0; st < 4; ++st) {
        sa[st] = att_s[colb + st * 16 + c15];
        da[st] = att_d[colb + st * 16 + c15];
    }
    #pragma unroll
    for (int r = 0; r < 4; ++r) {
        float ps = acc[0][r] * sa[0] + acc[1][r] * sa[1] + acc[2][r] * sa[2] + acc[3][r] * sa[3];
        float pd = acc[0][r] * da[0] + acc[1][r] * da[1] + acc[2][r] * da[2] + acc[3][r] * da[3];
        #pragma unroll
        for (int o = 1; o < 16; o <<= 1) {
            ps += __shfl_xor(ps, o);
            pd += __shfl_xor(pd, o);
        }
        int orow = row0 + wave * 16 + q * 4 + r;
        if (c15 == 0 && orow < M) {
            as_out[orow * 4 + blockIdx.y] = ps;
            ad_out[orow * 4 + blockIdx.y] = pd;
        }
    }
}

// ---------- MFMA bf16 GEMM, Nc=64 (pre0 / combine / jump) ----------
// C = alpha*(A@W) + bias [; BN; ELU][; +resid]. Optional:
//  - w_conv: W is a conv weight (64x256); stage V[k=h*64+r][n] = W[r*256+h*64+n]
//  - Cbf: also emit bf16 copy of final C (N x 64, contiguous)
//  - P (64x8 f32): fused next-layer attention dots -> as_out/ad_out (float4)
//  - attW/attb/wout: fused pool logits w = exp(C . attW + attb)
__global__ __launch_bounds__(256)
void gemm_n64_mfma(const void* __restrict__ Araw, int lda, int a_is_bf16,
                   const float* __restrict__ W, int w_conv, int M, int K, float alpha,
                   const float* __restrict__ bias,
                   float* __restrict__ C, int ldc, int mode,
                   const float* __restrict__ bn_g, const float* __restrict__ bn_b,
                   const float* __restrict__ bn_m, const float* __restrict__ bn_v,
                   const float* __restrict__ resid, int ldr,
                   const float* __restrict__ attW, const float* __restrict__ attb,
                   float* __restrict__ wout,
                   const float* __restrict__ P,
                   float* __restrict__ as_out, float* __restrict__ ad_out,
                   unsigned short* __restrict__ Cbf)
{
    __shared__ short Wt[64 * 264];           // max K=256 -> KP=264
    const int KP = K + 8;
    int tid  = threadIdx.x;
    int lane = tid & 63, wave = tid >> 6;
    int row0 = blockIdx.x * 64;
    int c15 = lane & 15, q = lane >> 4;

    {
        int n = tid & 63;
        for (int k = tid >> 6; k < K; k += 4) {
            float wv = w_conv ? W[(size_t)(k & 63) * 256 + (k >> 6) * 64 + n]
                              : W[(size_t)k * 64 + n];
            Wt[n * KP + k] = f2bf(wv);
        }
    }
    __syncthreads();

    int row = row0 + wave * 16 + c15;
    bool rok = row < M;

    f32x4 acc[4];
    #pragma unroll
    for (int st = 0; st < 4; ++st) acc[st] = (f32x4){0.f, 0.f, 0.f, 0.f};

    for (int k0 = 0; k0 < K; k0 += 32) {
        bf16x8 av;
        if (rok) {
            if (a_is_bf16) {
                av = *(const bf16x8*)((const unsigned short*)Araw
                                      + (size_t)row * lda + k0 + q * 8);
            } else {
                const float* ap = (const float*)Araw + (size_t)row * lda + k0 + q * 8;
                float4 a0 = *(const float4*)ap;
                float4 a1 = *(const float4*)(ap + 4);
                av[0] = f2bf(a0.x); av[1] = f2bf(a0.y); av[2] = f2bf(a0.z); av[3] = f2bf(a0.w);
                av[4] = f2bf(a1.x); av[5] = f2bf(a1.y); av[6] = f2bf(a1.z); av[7] = f2bf(a1.w);
            }
        } else {
            av = (bf16x8){0,0,0,0,0,0,0,0};
        }
        #pragma unroll
        for (int st = 0; st < 4; ++st) {
            bf16x8 bv = *(const bf16x8*)(Wt + (st * 16 + c15) * KP + k0 + q * 8);
            acc[st] = __builtin_amdgcn_mfma_f32_16x16x32_bf16(av, bv, acc[st], 0, 0, 0);
        }
    }

    #pragma unroll
    for (int st = 0; st < 4; ++st) {
        int col = st * 16 + c15;
        float bs = bias ? bias[col] : 0.f;
        float sg = 1.f, sb = 0.f;
        if (mode == 1) {
            sg = bn_g[col] / sqrtf(bn_v[col] + BNEPS);
            sb = bn_b[col] - bn_m[col] * sg;
        }
        #pragma unroll
        for (int r = 0; r < 4; ++r) {
            int orow = row0 + wave * 16 + q * 4 + r;
            if (orow >= M) continue;
            float v = alpha * acc[st][r] + bs;
            if (mode == 1) {
                v = v * sg + sb;
                v = v > 0.f ? v : __expf(v) - 1.f;
            }
            if (resid) v += resid[(size_t)orow * ldr + col];
            acc[st][r] = v;
            C[(size_t)orow * ldc + col] = v;
            if (Cbf) Cbf[(size_t)orow * 64 + col] = (unsigned short)f2bf(v);
        }
    }

    if (wout) {
        float sa[4];
        #pragma unroll
        for (int st = 0; st < 4; ++st) sa[st] = attW[st * 16 + c15];
        float ab = attb[0];
        #pragma unroll
        for (int r = 0; r < 4; ++r) {
            float ps = acc[0][r] * sa[0] + acc[1][r] * sa[1]
                     + acc[2][r] * sa[2] + acc[3][r] * sa[3];
            #pragma unroll
            for (int o = 1; o < 16; o <<= 1) ps += __shfl_xor(ps, o);
            int orow = row0 + wave * 16 + q * 4 + r;
            if (c15 == 0 && orow < M) wout[orow] = __expf(ps + ab);
        }
    }

    if (P) {
        float Ps[4][4], Pd[4][4];
        #pragma unroll
        for (int st = 0; st < 4; ++st) {
            int col = st * 16 + c15;
            #pragma unroll
            for (int h = 0; h < 4; ++h) {
                Ps[st][h] = P[col * 8 + h];
                Pd[st][h] = P[col * 8 + 4 + h];
            }
        }
        #pragma unroll
        for (int r = 0; r < 4; ++r) {
            float ps[4], pd[4];
            #pragma unroll
            for (int h = 0; h < 4; ++h) {
                float s = acc[0][r] * Ps[0][h] + acc[1][r] * Ps[1][h]
                        + acc[2][r] * Ps[2][h] + acc[3][r] * Ps[3][h];
                float d = acc[0][r] * Pd[0][h] + acc[1][r] * Pd[1][h]
                        + acc[2][r] * Pd[2][h] + acc[3][r] * Pd[3][h];
                #pragma unroll
                for (int o = 1; o < 16; o <<= 1) {
                    s += __shfl_xor(s, o);
                    d += __shfl_xor(d, o);
                }
                ps[h] = s; pd[h] = d;
            }
            int orow = row0 + wave * 16 + q * 4 + r;
            if (c15 == 0 && orow < M) {
                *(float4*)(as_out + orow * 4) = make_float4(ps[0], ps[1], ps[2], ps[3]);
                *(float4*)(ad_out + orow * 4) = make_float4(pd[0], pd[1], pd[2], pd[3]);
            }
        }
    }
}

// ---------- projected attention vectors: P[r*8+h]=W_h@att_s, P[r*8+4+h]=W_h@att_d ----------
// Wc is a conv weight (64 x 256). One block, 256 threads: thread = r*4 + h.
__global__ void proj_kernel(const float* __restrict__ Wc,
                            const float* __restrict__ att_s, const float* __restrict__ att_d,
                            float* __restrict__ P)
{
    int t = threadIdx.x;
    int r = t >> 2, h = t & 3;
    float s = 0.f, d = 0.f;
    for (int c = 0; c < 64; ++c) {
        float w = Wc[r * 256 + h * 64 + c];
        s += w * att_s[h * 64 + c];
        d += w * att_d[h * 64 + c];
    }
    P[r * 8 + h] = s;
    P[r * 8 + 4 + h] = d;
}

// ---------- CSR build: histogram over dst ----------
__global__ __launch_bounds__(256)
void hist_kernel(const int* __restrict__ ei, int E, int N, int* __restrict__ counts)
{
    int e = blockIdx.x * blockDim.x + threadIdx.x;
    int Etot = E + N;
    if (e >= Etot) return;
    int d = (e < E) ? ei[E + e] : e - E;
    atomicAdd(&counts[d], 1);
}

// ---------- scan phase 1 ----------
__global__ __launch_bounds__(256)
void scan_phase1(const int* __restrict__ counts, int N, int* __restrict__ blocksum)
{
    __shared__ int wsum[4];
    int tid = threadIdx.x, lane = tid & 63, wave = tid >> 6;
    int base = blockIdx.x * SCAN_CHUNK;
    int s = 0;
    #pragma unroll
    for (int j = 0; j < SCAN_CHUNK / 256; ++j) {
        int idx = base + tid + j * 256;
        if (idx < N) s += counts[idx];
    }
    #pragma unroll
    for (int o = 32; o; o >>= 1) s += __shfl_xor(s, o);
    if (lane == 0) wsum[wave] = s;
    __syncthreads();
    if (tid == 0) blocksum[blockIdx.x] = wsum[0] + wsum[1] + wsum[2] + wsum[3];
}

// ---------- scan phase 2 ----------
__global__ void scan_phase2(const int* __restrict__ blocksum, int nb,
                            int* __restrict__ blockoff, int* __restrict__ rowptr, int N)
{
    int lane = threadIdx.x;  // 64 threads
    int v = (lane < nb) ? blocksum[lane] : 0;
    int incl = v;
    #pragma unroll
    for (int o = 1; o < 64; o <<= 1) {
        int t = __shfl_up(incl, o);
        if (lane >= o) incl += t;
    }
    if (lane < nb) blockoff[lane + 1] = incl;
    if (lane == 0) blockoff[0] = 0;
    int total = __shfl(incl, nb - 1);
    if (lane == 0) rowptr[N] = total;
}

// ---------- scan phase 3 ----------
__global__ __launch_bounds__(256)
void scan_phase3(const int* __restrict__ counts, int N,
                 const int* __restrict__ blockoff,
                 int* __restrict__ rowptr, int* __restrict__ cursor)
{
    __shared__ int wsum[4];
    int tid = threadIdx.x, lane = tid & 63, wave = tid >> 6;
    int start = blockIdx.x * SCAN_CHUNK + tid * 8;
    int v[8];
    int s = 0;
    #pragma unroll
    for (int j = 0; j < 8; ++j) {
        v[j] = (start + j < N) ? counts[start + j] : 0;
        s += v[j];
    }
    int incl = s;
    #pragma unroll
    for (int o = 1; o < 64; o <<= 1) {
        int t = __shfl_up(incl, o);
        if (lane >= o) incl += t;
    }
    if (lane == 63) wsum[wave] = incl;
    __syncthreads();
    int woff = 0;
    #pragma unroll
    for (int w = 0; w < 4; ++w) if (w < wave) woff += wsum[w];
    int run = blockoff[blockIdx.x] + woff + incl - s;
    #pragma unroll
    for (int j = 0; j < 8; ++j) {
        int idx = start + j;
        if (idx < N) { rowptr[idx] = run; cursor[idx] = run; }
        run += v[j];
    }
}

// ---------- CSR build: scatter ----------
__global__ __launch_bounds__(256)
void scatter_kernel(const int* __restrict__ ei, int E, int N,
                    int* __restrict__ cursor, int* __restrict__ csr_src)
{
    int e = blockIdx.x * blockDim.x + threadIdx.x;
    int Etot = E + N;
    if (e >= Etot) return;
    int s, d;
    if (e < E) { s = ei[e]; d = ei[E + e]; } else { s = d = e - E; }
    int pos = atomicAdd(&cursor[d], 1);
    csr_src[pos] = s;
}

// ---------- layer-0 aggregation (v4, xh space, 512B/edge) ----------
// mode 0 only here: concat -> bf16 out (ushort4) with bias.
__global__ __launch_bounds__(256)
void aggregate_kernel(const int* __restrict__ rowptr, const int* __restrict__ csr_src,
                      const float* __restrict__ as_n, const float* __restrict__ ad_n,
                      const unsigned short* __restrict__ xh,
                      const float* __restrict__ bias,
                      unsigned short* __restrict__ outbf, int N)
{
    int node = (blockIdx.x * blockDim.x + threadIdx.x) >> 6;
    int lane = threadIdx.x & 63;
    if (node >= N) return;
    int h = lane >> 4, li = lane & 15, grp = lane & 48;
    int e0 = rowptr[node], e1 = rowptr[node + 1];
    float adh = ad_n[node * 4 + h];

    float4 acc = make_float4(0.f, 0.f, 0.f, 0.f);
    float wsum = 0.f;

    for (int base = e0; base < e1; base += 16) {
        int cnt = e1 - base; if (cnt > 16) cnt = 16;
        int s = 0; float w = 0.f;
        if (li < cnt) {
            s = csr_src[base + li];
            float l = as_n[s * 4 + h] + adh;
            l = fmaxf(l, NEG * l);
            w = __expf(l);
        }
        int k = 0;
        for (; k + 3 < cnt; k += 4) {
            float w0 = __shfl(w, grp + k),     w1 = __shfl(w, grp + k + 1);
            float w2 = __shfl(w, grp + k + 2), w3 = __shfl(w, grp + k + 3);
            int s0 = __shfl(s, grp + k),       s1 = __shfl(s, grp + k + 1);
            int s2 = __shfl(s, grp + k + 2),   s3 = __shfl(s, grp + k + 3);
            ushort4 xv0 = *(const ushort4*)(xh + (size_t)s0 * 256 + lane * 4);
            ushort4 xv1 = *(const ushort4*)(xh + (size_t)s1 * 256 + lane * 4);
            ushort4 xv2 = *(const ushort4*)(xh + (size_t)s2 * 256 + lane * 4);
            ushort4 xv3 = *(const ushort4*)(xh + (size_t)s3 * 256 + lane * 4);
            acc.x += w0 * bf2f(xv0.x); acc.y += w0 * bf2f(xv0.y);
            acc.z += w0 * bf2f(xv0.z); acc.w += w0 * bf2f(xv0.w);
            acc.x += w1 * bf2f(xv1.x); acc.y += w1 * bf2f(xv1.y);
            acc.z += w1 * bf2f(xv1.z); acc.w += w1 * bf2f(xv1.w);
            acc.x += w2 * bf2f(xv2.x); acc.y += w2 * bf2f(xv2.y);
            acc.z += w2 * bf2f(xv2.z); acc.w += w2 * bf2f(xv2.w);
            acc.x += w3 * bf2f(xv3.x); acc.y += w3 * bf2f(xv3.y);
            acc.z += w3 * bf2f(xv3.z); acc.w += w3 * bf2f(xv3.w);
            wsum += (w0 + w1) + (w2 + w3);
        }
        for (; k < cnt; ++k) {
            float wk = __shfl(w, grp + k);
            int sk = __shfl(s, grp + k);
            ushort4 xv = *(const ushort4*)(xh + (size_t)sk * 256 + lane * 4);
            acc.x += wk * bf2f(xv.x); acc.y += wk * bf2f(xv.y);
            acc.z += wk * bf2f(xv.z); acc.w += wk * bf2f(xv.w);
            wsum += wk;
        }
    }

    float rw = 1.f / wsum;
    float4 bs = *(const float4*)(bias + lane * 4);
    ushort4 pk;
    pk.x = (unsigned short)f2bf(acc.x * rw + bs.x);
    pk.y = (unsigned short)f2bf(acc.y * rw + bs.y);
    pk.z = (unsigned short)f2bf(acc.z * rw + bs.z);
    pk.w = (unsigned short)f2bf(acc.w * rw + bs.w);
    *(ushort4*)(outbf + (size_t)node * 256 + lane * 4) = pk;
}

// ---------- layers-1/2 aggregation in REP space (128B/edge gather) ----------
// Gathers 64-dim bf16 rep rows; per-head weighted sums -> normagg bf16 N x 256
// laid out A[n, h*64 + r] (head-major) = lane*4 chunk, no bias (folded later).
__global__ __launch_bounds__(256)
void aggregate_rep_kernel(const int* __restrict__ rowptr, const int* __restrict__ csr_src,
                          const float* __restrict__ as_n, const float* __restrict__ ad_n,
                          const unsigned short* __restrict__ repbf,
                          unsigned short* __restrict__ outbf, int N)
{
    int node = (blockIdx.x * blockDim.x + threadIdx.x) >> 6;
    int lane = threadIdx.x & 63;
    if (node >= N) return;
    int h = lane >> 4, li = lane & 15, grp = lane & 48;
    int e0 = rowptr[node], e1 = rowptr[node + 1];
    float adh = ad_n[node * 4 + h];

    float4 acc = make_float4(0.f, 0.f, 0.f, 0.f);
    float wsum = 0.f;

    for (int base = e0; base < e1; base += 16) {
        int cnt = e1 - base; if (cnt > 16) cnt = 16;
        int s = 0; float w = 0.f;
        if (li < cnt) {
            s = csr_src[base + li];
            float l = as_n[s * 4 + h] + adh;
            l = fmaxf(l, NEG * l);
            w = __expf(l);
        }
        int k = 0;
        for (; k + 3 < cnt; k += 4) {
            float w0 = __shfl(w, grp + k),     w1 = __shfl(w, grp + k + 1);
            float w2 = __shfl(w, grp + k + 2), w3 = __shfl(w, grp + k + 3);
            int s0 = __shfl(s, grp + k),       s1 = __shfl(s, grp + k + 1);
            int s2 = __shfl(s, grp + k + 2),   s3 = __shfl(s, grp + k + 3);
            ushort4 xv0 = *(const ushort4*)(repbf + (size_t)s0 * 64 + li * 4);
            ushort4 xv1 = *(const ushort4*)(repbf + (size_t)s1 * 64 + li * 4);
            ushort4 xv2 = *(const ushort4*)(repbf + (size_t)s2 * 64 + li * 4);
            ushort4 xv3 = *(const ushort4*)(repbf + (size_t)s3 * 64 + li * 4);
            acc.x += w0 * bf2f(xv0.x); acc.y += w0 * bf2f(xv0.y);
            acc.z += w0 * bf2f(xv0.z); acc.w += w0 * bf2f(xv0.w);
            acc.x += w1 * bf2f(xv1.x); acc.y += w1 * bf2f(xv1.y);
            acc.z += w1 * bf2f(xv1.z); acc.w += w1 * bf2f(xv1.w);
            acc.x += w2 * bf2f(xv2.x); acc.y += w2 * bf2f(xv2.y);
            acc.z += w2 * bf2f(xv2.z); acc.w += w2 * bf2f(xv2.w);
            acc.x += w3 * bf2f(xv3.x); acc.y += w3 * bf2f(xv3.y);
            acc.z += w3 * bf2f(xv3.z); acc.w += w3 * bf2f(xv3.w);
            wsum += (w0 + w1) + (w2 + w3);
        }
        for (; k < cnt; ++k) {
            float wk = __shfl(w, grp + k);
            int sk = __shfl(s, grp + k);
            ushort4 xv = *(const ushort4*)(repbf + (size_t)sk * 64 + li * 4);
            acc.x += wk * bf2f(xv.x); acc.y += wk * bf2f(xv.y);
            acc.z += wk * bf2f(xv.z); acc.w += wk * bf2f(xv.w);
            wsum += wk;
        }
    }

    float rw = 1.f / wsum;
    ushort4 pk;
    pk.x = (unsigned short)f2bf(acc.x * rw);
    pk.y = (unsigned short)f2bf(acc.y * rw);
    pk.z = (unsigned short)f2bf(acc.z * rw);
    pk.w = (unsigned short)f2bf(acc.w * rw);
    *(ushort4*)(outbf + (size_t)node * 256 + lane * 4) = pk;
}

// ---------- graph boundaries + pool-accumulator zeroing (fused) ----------
__global__ void gstart_kernel(const int* __restrict__ batch, int N, int* __restrict__ gstart,
                              float* __restrict__ hg_acc, float* __restrict__ wsum_acc)
{
    int t = threadIdx.x;   // 128 threads
    for (int idx = t; idx < NGRAPH * 64; idx += 128) hg_acc[idx] = 0.f;
    if (t < NGRAPH) wsum_acc[t] = 0.f;
    if (t <= NGRAPH) {
        int lo = 0, hi = N;
        while (lo < hi) {
            int mid = (lo + hi) >> 1;
            if (batch[mid] < t) lo = mid + 1; else hi = mid;
        }
        gstart[t] = lo;
    }
}

// ---------- pooling partial sums ----------
__global__ __launch_bounds__(256)
void pool_partial(const float* __restrict__ hjk, const float* __restrict__ w,
                  const int* __restrict__ batch, const int* __restrict__ gstart,
                  float* __restrict__ hg_acc, float* __restrict__ wsum_acc, int N)
{
    __shared__ float red[256];
    __shared__ float wred[4];
    int tid = threadIdx.x;
    int c = tid & 63, q = tid >> 6;
    int slab = (N + POOL_BLOCKS - 1) / POOL_BLOCKS;
    int n0 = blockIdx.x * slab;
    int n1 = n0 + slab; if (n1 > N) n1 = N;
    if (n0 >= n1) return;
    int g0 = batch[n0], g1 = batch[n1 - 1];

    for (int g = g0; g <= g1; ++g) {
        int s = gstart[g];     if (s < n0) s = n0;
        int e = gstart[g + 1]; if (e > n1) e = n1;
        float acc = 0.f, ws = 0.f;
        for (int n = s + q; n < e; n += 4) {
            float wn = w[n];
            acc += wn * hjk[(size_t)n * 64 + c];
            if (c == 0) ws += wn;
        }
        red[tid] = acc;
        if (c == 0) wred[q] = ws;
        __syncthreads();
        if (q == 0) {
            float v = red[c] + red[64 + c] + red[128 + c] + red[192 + c];
            if (v != 0.f) atomicAdd(&hg_acc[g * 64 + c], v);
            if (c == 0) {
                float t = wred[0] + wred[1] + wred[2] + wred[3];
                if (t != 0.f) atomicAdd(&wsum_acc[g], t);
            }
        }
        __syncthreads();
    }
}

// ---------- classifier head ----------
__global__ void cls_kernel(const float* __restrict__ hg_acc,
                           const float* __restrict__ wsum_acc,
                           const float* __restrict__ W1, const float* __restrict__ b1,
                           const float* __restrict__ W2, const float* __restrict__ b2,
                           float* __restrict__ out)
{
    int g = blockIdx.x, t = threadIdx.x;  // 32 threads
    __shared__ float z[32];
    __shared__ float h[64];
    float wsum = wsum_acc[g];
    float rw = (wsum > 0.f) ? 1.f / wsum : 0.f;
    h[t] = hg_acc[g * 64 + t] * rw;
    h[t + 32] = hg_acc[g * 64 + t + 32] * rw;
    __syncthreads();
    float acc = b1[t];
    for (int k = 0; k < 64; ++k) acc += h[k] * W1[k * 32 + t];
    z[t] = fmaxf(acc, 0.f);
    __syncthreads();
    if (t < 2) {
        float o = b2[t];
        for (int j = 0; j < 32; ++j) o += z[j] * W2[j * 2 + t];
        out[g * 2 + t] = o;
    }
}

extern "C" void kernel_launch(void* const* d_in, const int* in_sizes, int n_in,
                              void* d_out, int out_size, void* d_ws, size_t ws_size,
                              hipStream_t stream)
{
    const float* x        = (const float*)d_in[0];
    const int*   ei       = (const int*)d_in[1];
    const int*   batch    = (const int*)d_in[2];
    const float* conv0_W  = (const float*)d_in[3];
    const float* conv0_as = (const float*)d_in[4];
    const float* conv0_ad = (const float*)d_in[5];
    const float* conv0_b  = (const float*)d_in[6];
    const float* pre0_W   = (const float*)d_in[7];
    const float* pre0_b   = (const float*)d_in[8];
    const float* convs_W  = (const float*)d_in[9];
    const float* convs_as = (const float*)d_in[10];
    const float* convs_ad = (const float*)d_in[11];
    const float* convs_b  = (const float*)d_in[12];
    const float* bn_g     = (const float*)d_in[13];
    const float* bn_b     = (const float*)d_in[14];
    const float* bn_m     = (const float*)d_in[15];
    const float* bn_v     = (const float*)d_in[16];
    const float* jump_W   = (const float*)d_in[17];
    const float* jump_b   = (const float*)d_in[18];
    const float* att_W    = (const float*)d_in[19];
    const float* att_b    = (const float*)d_in[20];
    const float* cls_W1   = (const float*)d_in[21];
    const float* cls_b1   = (const float*)d_in[22];
    const float* cls_W2   = (const float*)d_in[23];
    const float* cls_b2   = (const float*)d_in[24];
    float* out = (float*)d_out;

    const int N = in_sizes[0] / 128;   // 50000
    const int E = in_sizes[1] / 2;     // 400000
    const int Etot = E + N;
    const int nb = (N + SCAN_CHUNK - 1) / SCAN_CHUNK;   // 25 <= 64

    // workspace layout
    float* ws      = (float*)d_ws;
    unsigned short* xh_bf   = (unsigned short*)ws;          // N*256 bf16 (xh / normagg)
    unsigned short* h256_bf = xh_bf + (size_t)N * 256;      // N*256 bf16 (layer-0 concat)
    unsigned short* repbf   = h256_bf + (size_t)N * 256;    // N*64 bf16 (rep rows)
    float* repsAll = (float*)(repbf + (size_t)N * 64);      // N*192 f32
    float* as_n    = repsAll + (size_t)N * 192;             // N*4
    float* ad_n    = as_n + (size_t)N * 4;                  // N*4
    float* hjk     = ad_n + (size_t)N * 4;                  // N*64
    float* P1      = hjk + (size_t)N * 64;                  // 64*8
    float* P2      = P1 + 512;                              // 64*8
    float* hg_acc  = P2 + 512;                              // 64*64
    float* wsum_acc= hg_acc + NGRAPH * 64;                  // 64
    int*   rowptr  = (int*)(wsum_acc + NGRAPH);             // N+1
    int*   cursor  = rowptr + (N + 1);                      // N
    int*   counts  = cursor + N;                            // N
    int*   csr_src = counts + N;                            // Etot
    int*   gstart  = csr_src + Etot;                        // 65
    int*   blocksum = gstart + (NGRAPH + 1);                // 64
    int*   blockoff = blocksum + 64;                        // 65
    float* wbuf    = as_n;  // reuse (free after last layer)

    dim3 blk(256);
    int node_wave_blocks = (N + 3) / 4;
    int edge_blocks      = (Etot + 255) / 256;
    int row_blocks       = (N + 63) / 64;

    // ---------------- CSR build + P precompute ----------------
    hipMemsetAsync(counts, 0, (size_t)N * sizeof(int), stream);
    hist_kernel<<<edge_blocks, blk, 0, stream>>>(ei, E, N, counts);
    scan_phase1<<<nb, blk, 0, stream>>>(counts, N, blocksum);
    scan_phase2<<<1, 64, 0, stream>>>(blocksum, nb, blockoff, rowptr, N);
    scan_phase3<<<nb, blk, 0, stream>>>(counts, N, blockoff, rowptr, cursor);
    scatter_kernel<<<edge_blocks, blk, 0, stream>>>(ei, E, N, cursor, csr_src);
    proj_kernel<<<1, 256, 0, stream>>>(convs_W, convs_as, convs_ad, P1);
    proj_kernel<<<1, 256, 0, stream>>>(convs_W + 64 * 256, convs_as + 256,
                                       convs_ad + 256, P2);

    // ---------------- layer 0 (xh space) ----------------
    {
        dim3 g1(row_blocks, 4);
        gemm_xh_mfma<<<g1, blk, 0, stream>>>(x, 128, conv0_W, 256, N, 128,
                                             conv0_as, conv0_ad, as_n, ad_n, xh_bf);
        aggregate_kernel<<<node_wave_blocks, blk, 0, stream>>>(
            rowptr, csr_src, as_n, ad_n, xh_bf, conv0_b, h256_bf, N);
        // pre0: rep1 = ELU(BN(h256 @ pre0_W + pre0_b)); emit rep1 bf16 + layer-1 dots
        gemm_n64_mfma<<<row_blocks, blk, 0, stream>>>(
            h256_bf, 256, 1, pre0_W, 0, N, 256, 1.f, pre0_b,
            repsAll, 192, 1, bn_g, bn_b, bn_m, bn_v,
            nullptr, 0, nullptr, nullptr, nullptr,
            P1, as_n, ad_n, repbf);
    }

    // ---------------- layers 1, 2 (rep space) ----------------
    for (int i = 0; i < 2; ++i) {
        aggregate_rep_kernel<<<node_wave_blocks, blk, 0, stream>>>(
            rowptr, csr_src, as_n, ad_n, repbf, xh_bf, N);
        gemm_n64_mfma<<<row_blocks, blk, 0, stream>>>(
            xh_bf, 256, 1, convs_W + (size_t)i * 64 * 256, 1, N, 256, 0.25f,
            convs_b + i * 64,
            repsAll + (i + 1) * 64, 192, 1,
            bn_g + (i + 1) * 64, bn_b + (i + 1) * 64,
            bn_m + (i + 1) * 64, bn_v + (i + 1) * 64,
            repsAll + i * 64, 192,
            nullptr, nullptr, nullptr,
            (i == 0) ? P2 : nullptr, as_n, ad_n,
            (i == 0) ? repbf : nullptr);
    }

    // ---------------- JK projection + fused pool logits ----------------
    gemm_n64_mfma<<<row_blocks, blk, 0, stream>>>(
        repsAll, 192, 0, jump_W, 0, N, 192, 1.f, jump_b,
        hjk, 64, 0, nullptr, nullptr, nullptr, nullptr,
        nullptr, 0, att_W, att_b, wbuf,
        nullptr, nullptr, nullptr, nullptr);

    // ---------------- pooling + classifier ----------------
    gstart_kernel<<<1, 128, 0, stream>>>(batch, N, gstart, hg_acc, wsum_acc);
    pool_partial<<<POOL_BLOCKS, blk, 0, stream>>>(hjk, wbuf, batch, gstart,
                                                  hg_acc, wsum_acc, N);
    cls_kernel<<<NGRAPH, 32, 0, stream>>>(hg_acc, wsum_acc, cls_W1, cls_b1,
                                          cls_W2, cls_b2, out);
}

// Round 15
// 413.128 us; speedup vs baseline: 1.0146x; 1.0146x over previous
//
#include <hip/hip_runtime.h>
#include <hip/hip_bf16.h>
#include <math.h>

#define NEG 0.2f
#define BNEPS 1e-5f
#define NGRAPH 64
#define SCAN_CHUNK 2048
#define POOL_BLOCKS 256

typedef short bf16x8 __attribute__((ext_vector_type(8)));            // 8 bf16 (4 VGPRs)
typedef float f32x4  __attribute__((ext_vector_type(4)));            // MFMA accumulator

__device__ __forceinline__ float bf2f(unsigned short u) {
    return __uint_as_float(((unsigned)u) << 16);
}
__device__ __forceinline__ short f2bf(float f) {
    return (short)__bfloat16_as_ushort(__float2bfloat16(f));
}

// ---------- MFMA bf16 GEMM for xh: Cbf[M,256] = bf16(A[M,K] @ W[K,256]) ----------
// + fused attention dots. grid (ceil(M/64), 4), block 256. head = blockIdx.y.
__global__ __launch_bounds__(256)
void gemm_xh_mfma(const float* __restrict__ A, int lda,
                  const float* __restrict__ W, int Nc, int M, int K,
                  const float* __restrict__ att_s, const float* __restrict__ att_d,
                  float* __restrict__ as_out, float* __restrict__ ad_out,
                  unsigned short* __restrict__ Cbf)
{
    __shared__ short Wt[64 * 136];           // max K=128 -> KP=136
    const int KP = K + 8;
    int tid  = threadIdx.x;
    int lane = tid & 63, wave = tid >> 6;
    int row0 = blockIdx.x * 64;
    int colb = blockIdx.y * 64;
    int c15 = lane & 15, q = lane >> 4;

    {
        int n = tid & 63;
        for (int k = tid >> 6; k < K; k += 4)
            Wt[n * KP + k] = f2bf(W[(size_t)k * Nc + colb + n]);
    }
    __syncthreads();

    int row = row0 + wave * 16 + c15;
    bool rok = row < M;
    const float* arow = A + (size_t)row * lda + q * 8;

    f32x4 acc[4];
    #pragma unroll
    for (int st = 0; st < 4; ++st) acc[st] = (f32x4){0.f, 0.f, 0.f, 0.f};

    for (int k0 = 0; k0 < K; k0 += 32) {
        bf16x8 av;
        if (rok) {
            float4 a0 = *(const float4*)(arow + k0);
            float4 a1 = *(const float4*)(arow + k0 + 4);
            av[0] = f2bf(a0.x); av[1] = f2bf(a0.y); av[2] = f2bf(a0.z); av[3] = f2bf(a0.w);
            av[4] = f2bf(a1.x); av[5] = f2bf(a1.y); av[6] = f2bf(a1.z); av[7] = f2bf(a1.w);
        } else {
            av = (bf16x8){0,0,0,0,0,0,0,0};
        }
        #pragma unroll
        for (int st = 0; st < 4; ++st) {
            bf16x8 bv = *(const bf16x8*)(Wt + (st * 16 + c15) * KP + k0 + q * 8);
            acc[st] = __builtin_amdgcn_mfma_f32_16x16x32_bf16(av, bv, acc[st], 0, 0, 0);
        }
    }

    #pragma unroll
    for (int r = 0; r < 4; ++r) {
        int orow = row0 + wave * 16 + q * 4 + r;
        if (orow >= M) continue;
        unsigned short* cb = Cbf + (size_t)orow * 256 + colb + c15;
        #pragma unroll
        for (int st = 0; st < 4; ++st)
            cb[st * 16] = (unsigned short)f2bf(acc[st][r]);
    }
    float sa[4], da[4];
    #pragma unroll
    for (int st = 0; st < 4; ++st) {
        sa[st] = att_s[colb + st * 16 + c15];
        da[st] = att_d[colb + st * 16 + c15];
    }
    #pragma unroll
    for (int r = 0; r < 4; ++r) {
        float ps = acc[0][r] * sa[0] + acc[1][r] * sa[1] + acc[2][r] * sa[2] + acc[3][r] * sa[3];
        float pd = acc[0][r] * da[0] + acc[1][r] * da[1] + acc[2][r] * da[2] + acc[3][r] * da[3];
        #pragma unroll
        for (int o = 1; o < 16; o <<= 1) {
            ps += __shfl_xor(ps, o);
            pd += __shfl_xor(pd, o);
        }
        int orow = row0 + wave * 16 + q * 4 + r;
        if (c15 == 0 && orow < M) {
            as_out[orow * 4 + blockIdx.y] = ps;
            ad_out[orow * 4 + blockIdx.y] = pd;
        }
    }
}

// ---------- MFMA bf16 GEMM, Nc=64 (pre0 / jump) + optional fused pool logits ----------
__global__ __launch_bounds__(256)
void gemm_n64_mfma(const void* __restrict__ Araw, int lda, int a_is_bf16,
                   const float* __restrict__ W, int M, int K,
                   const float* __restrict__ bias,
                   float* __restrict__ C, int ldc, int mode,
                   const float* __restrict__ bn_g, const float* __restrict__ bn_b,
                   const float* __restrict__ bn_m, const float* __restrict__ bn_v,
                   const float* __restrict__ attW, const float* __restrict__ attb,
                   float* __restrict__ wout)
{
    __shared__ short Wt[64 * 264];           // max K=256 -> KP=264
    const int KP = K + 8;
    int tid  = threadIdx.x;
    int lane = tid & 63, wave = tid >> 6;
    int row0 = blockIdx.x * 64;
    int c15 = lane & 15, q = lane >> 4;

    {
        int n = tid & 63;
        for (int k = tid >> 6; k < K; k += 4)
            Wt[n * KP + k] = f2bf(W[(size_t)k * 64 + n]);
    }
    __syncthreads();

    int row = row0 + wave * 16 + c15;
    bool rok = row < M;

    f32x4 acc[4];
    #pragma unroll
    for (int st = 0; st < 4; ++st) acc[st] = (f32x4){0.f, 0.f, 0.f, 0.f};

    for (int k0 = 0; k0 < K; k0 += 32) {
        bf16x8 av;
        if (rok) {
            if (a_is_bf16) {
                av = *(const bf16x8*)((const unsigned short*)Araw
                                      + (size_t)row * lda + k0 + q * 8);
            } else {
                const float* ap = (const float*)Araw + (size_t)row * lda + k0 + q * 8;
                float4 a0 = *(const float4*)ap;
                float4 a1 = *(const float4*)(ap + 4);
                av[0] = f2bf(a0.x); av[1] = f2bf(a0.y); av[2] = f2bf(a0.z); av[3] = f2bf(a0.w);
                av[4] = f2bf(a1.x); av[5] = f2bf(a1.y); av[6] = f2bf(a1.z); av[7] = f2bf(a1.w);
            }
        } else {
            av = (bf16x8){0,0,0,0,0,0,0,0};
        }
        #pragma unroll
        for (int st = 0; st < 4; ++st) {
            bf16x8 bv = *(const bf16x8*)(Wt + (st * 16 + c15) * KP + k0 + q * 8);
            acc[st] = __builtin_amdgcn_mfma_f32_16x16x32_bf16(av, bv, acc[st], 0, 0, 0);
        }
    }

    #pragma unroll
    for (int st = 0; st < 4; ++st) {
        int col = st * 16 + c15;
        float bs = bias ? bias[col] : 0.f;
        float sg = 1.f, sb = 0.f;
        if (mode == 1) {
            sg = bn_g[col] / sqrtf(bn_v[col] + BNEPS);
            sb = bn_b[col] - bn_m[col] * sg;
        }
        #pragma unroll
        for (int r = 0; r < 4; ++r) {
            int orow = row0 + wave * 16 + q * 4 + r;
            if (orow >= M) continue;
            float v = acc[st][r] + bs;
            if (mode == 1) {
                v = v * sg + sb;
                v = v > 0.f ? v : __expf(v) - 1.f;
            }
            acc[st][r] = v;
            C[(size_t)orow * ldc + col] = v;
        }
    }

    if (wout) {
        float sa[4];
        #pragma unroll
        for (int st = 0; st < 4; ++st) sa[st] = attW[st * 16 + c15];
        float ab = attb[0];
        #pragma unroll
        for (int r = 0; r < 4; ++r) {
            float ps = acc[0][r] * sa[0] + acc[1][r] * sa[1]
                     + acc[2][r] * sa[2] + acc[3][r] * sa[3];
            #pragma unroll
            for (int o = 1; o < 16; o <<= 1) ps += __shfl_xor(ps, o);
            int orow = row0 + wave * 16 + q * 4 + r;
            if (c15 == 0 && orow < M) wout[orow] = __expf(ps + ab);
        }
    }
}

// ---------- CSR build: histogram over dst ----------
__global__ __launch_bounds__(256)
void hist_kernel(const int* __restrict__ ei, int E, int N, int* __restrict__ counts)
{
    int e = blockIdx.x * blockDim.x + threadIdx.x;
    int Etot = E + N;
    if (e >= Etot) return;
    int d = (e < E) ? ei[E + e] : e - E;
    atomicAdd(&counts[d], 1);
}

// ---------- scan phase 1: per-block partial sums ----------
__global__ __launch_bounds__(256)
void scan_phase1(const int* __restrict__ counts, int N, int* __restrict__ blocksum)
{
    __shared__ int wsum[4];
    int tid = threadIdx.x, lane = tid & 63, wave = tid >> 6;
    int base = blockIdx.x * SCAN_CHUNK;
    int s = 0;
    #pragma unroll
    for (int j = 0; j < SCAN_CHUNK / 256; ++j) {
        int idx = base + tid + j * 256;
        if (idx < N) s += counts[idx];
    }
    #pragma unroll
    for (int o = 32; o; o >>= 1) s += __shfl_xor(s, o);
    if (lane == 0) wsum[wave] = s;
    __syncthreads();
    if (tid == 0) blocksum[blockIdx.x] = wsum[0] + wsum[1] + wsum[2] + wsum[3];
}

// ---------- scan phase 3 (merged with global prefix of block sums) ----------
// wave 0 rescans blocksum[0..nb) locally -> no separate phase-2 dispatch.
__global__ __launch_bounds__(256)
void scan_phase3(const int* __restrict__ counts, int N, int nb,
                 const int* __restrict__ blocksum,
                 int* __restrict__ rowptr, int* __restrict__ cursor)
{
    __shared__ int wsum[4];
    __shared__ int pref[64];
    int tid = threadIdx.x, lane = tid & 63, wave = tid >> 6;

    if (wave == 0) {
        int v = (lane < nb) ? blocksum[lane] : 0;
        int incl = v;
        #pragma unroll
        for (int o = 1; o < 64; o <<= 1) {
            int t = __shfl_up(incl, o);
            if (lane >= o) incl += t;
        }
        pref[lane] = incl;
    }
    __syncthreads();
    int boff = blockIdx.x ? pref[blockIdx.x - 1] : 0;
    if (blockIdx.x == 0 && tid == 0) rowptr[N] = pref[nb - 1];

    int start = blockIdx.x * SCAN_CHUNK + tid * 8;
    int v[8];
    int s = 0;
    #pragma unroll
    for (int j = 0; j < 8; ++j) {
        v[j] = (start + j < N) ? counts[start + j] : 0;
        s += v[j];
    }
    int incl = s;
    #pragma unroll
    for (int o = 1; o < 64; o <<= 1) {
        int t = __shfl_up(incl, o);
        if (lane >= o) incl += t;
    }
    if (lane == 63) wsum[wave] = incl;
    __syncthreads();
    int woff = 0;
    #pragma unroll
    for (int w = 0; w < 4; ++w) if (w < wave) woff += wsum[w];
    int run = boff + woff + incl - s;
    #pragma unroll
    for (int j = 0; j < 8; ++j) {
        int idx = start + j;
        if (idx < N) { rowptr[idx] = run; cursor[idx] = run; }
        run += v[j];
    }
}

// ---------- CSR build: scatter ----------
__global__ __launch_bounds__(256)
void scatter_kernel(const int* __restrict__ ei, int E, int N,
                    int* __restrict__ cursor, int* __restrict__ csr_src)
{
    int e = blockIdx.x * blockDim.x + threadIdx.x;
    int Etot = E + N;
    if (e >= Etot) return;
    int s, d;
    if (e < E) { s = ei[e]; d = ei[E + e]; } else { s = d = e - E; }
    int pos = atomicAdd(&cursor[d], 1);
    csr_src[pos] = s;
}

// ---------- fused per-node GAT aggregation v4 (in-register shfl weights) ----------
// One wave per node. Phase A: lane (h=lane>>4, i=lane&15) computes head-h
// softmax weight for edge e0+i. Phase B: channel-parallel, shfl-broadcast
// weight/src, 4-deep ILP, 32-bit byte-offset gather addressing.
// mode 0: concat -> bf16 out (ushort4); mode 1: head-mean epilogue -> f32.
__global__ __launch_bounds__(256)
void aggregate_kernel(const int* __restrict__ rowptr, const int* __restrict__ csr_src,
                      const float* __restrict__ as_n, const float* __restrict__ ad_n,
                      const unsigned short* __restrict__ xh,
                      const float* __restrict__ bias,
                      float* __restrict__ outp, int ldo,
                      int N, int mode,
                      const float* __restrict__ bn_g, const float* __restrict__ bn_b,
                      const float* __restrict__ bn_m, const float* __restrict__ bn_v,
                      const float* __restrict__ resid)
{
    int node = (blockIdx.x * blockDim.x + threadIdx.x) >> 6;
    int lane = threadIdx.x & 63;
    if (node >= N) return;
    int h = lane >> 4, li = lane & 15, grp = lane & 48;
    int e0 = rowptr[node], e1 = rowptr[node + 1];
    float adh = ad_n[node * 4 + h];
    const unsigned char* xb = (const unsigned char*)xh;
    unsigned laneoff = (unsigned)(lane * 8);

    float4 acc = make_float4(0.f, 0.f, 0.f, 0.f);
    float wsum = 0.f;

    for (int base = e0; base < e1; base += 16) {
        int cnt = e1 - base; if (cnt > 16) cnt = 16;
        // phase A: this lane's head-h weight for edge base+li
        int s = 0; float w = 0.f;
        if (li < cnt) {
            s = csr_src[base + li];
            float l = as_n[s * 4 + h] + adh;
            l = fmaxf(l, NEG * l);
            w = __expf(l);
        }
        // phase B: channel-parallel accumulation, 4-deep ILP
        int k = 0;
        for (; k + 3 < cnt; k += 4) {
            float w0 = __shfl(w, grp + k),     w1 = __shfl(w, grp + k + 1);
            float w2 = __shfl(w, grp + k + 2), w3 = __shfl(w, grp + k + 3);
            int s0 = __shfl(s, grp + k),       s1 = __shfl(s, grp + k + 1);
            int s2 = __shfl(s, grp + k + 2),   s3 = __shfl(s, grp + k + 3);
            ushort4 xv0 = *(const ushort4*)(xb + ((unsigned)s0 * 512u + laneoff));
            ushort4 xv1 = *(const ushort4*)(xb + ((unsigned)s1 * 512u + laneoff));
            ushort4 xv2 = *(const ushort4*)(xb + ((unsigned)s2 * 512u + laneoff));
            ushort4 xv3 = *(const ushort4*)(xb + ((unsigned)s3 * 512u + laneoff));
            acc.x += w0 * bf2f(xv0.x); acc.y += w0 * bf2f(xv0.y);
            acc.z += w0 * bf2f(xv0.z); acc.w += w0 * bf2f(xv0.w);
            acc.x += w1 * bf2f(xv1.x); acc.y += w1 * bf2f(xv1.y);
            acc.z += w1 * bf2f(xv1.z); acc.w += w1 * bf2f(xv1.w);
            acc.x += w2 * bf2f(xv2.x); acc.y += w2 * bf2f(xv2.y);
            acc.z += w2 * bf2f(xv2.z); acc.w += w2 * bf2f(xv2.w);
            acc.x += w3 * bf2f(xv3.x); acc.y += w3 * bf2f(xv3.y);
            acc.z += w3 * bf2f(xv3.z); acc.w += w3 * bf2f(xv3.w);
            wsum += (w0 + w1) + (w2 + w3);
        }
        for (; k < cnt; ++k) {
            float wk = __shfl(w, grp + k);
            int sk = __shfl(s, grp + k);
            ushort4 xv = *(const ushort4*)(xb + ((unsigned)sk * 512u + laneoff));
            acc.x += wk * bf2f(xv.x); acc.y += wk * bf2f(xv.y);
            acc.z += wk * bf2f(xv.z); acc.w += wk * bf2f(xv.w);
            wsum += wk;
        }
    }

    float rw = 1.f / wsum;
    acc.x *= rw; acc.y *= rw; acc.z *= rw; acc.w *= rw;

    if (mode == 0) {
        float4 bs = *(const float4*)(bias + lane * 4);
        ushort4 pk;
        pk.x = (unsigned short)f2bf(acc.x + bs.x);
        pk.y = (unsigned short)f2bf(acc.y + bs.y);
        pk.z = (unsigned short)f2bf(acc.z + bs.z);
        pk.w = (unsigned short)f2bf(acc.w + bs.w);
        *(ushort4*)((unsigned short*)outp + (size_t)node * 256 + lane * 4) = pk;
    } else {
        #pragma unroll
        for (int off = 16; off <= 32; off <<= 1) {
            acc.x += __shfl_xor(acc.x, off);
            acc.y += __shfl_xor(acc.y, off);
            acc.z += __shfl_xor(acc.z, off);
            acc.w += __shfl_xor(acc.w, off);
        }
        if (lane < 16) {
            int cin = lane * 4;
            float4 bs = *(const float4*)(bias + cin);
            float4 g = *(const float4*)(bn_g + cin);
            float4 b = *(const float4*)(bn_b + cin);
            float4 m = *(const float4*)(bn_m + cin);
            float4 vv = *(const float4*)(bn_v + cin);
            float4 rs = *(const float4*)(resid + (size_t)node * ldo + cin);
            float o[4] = {acc.x, acc.y, acc.z, acc.w};
            float bb[4] = {bs.x, bs.y, bs.z, bs.w};
            float gg[4] = {g.x, g.y, g.z, g.w};
            float be[4] = {b.x, b.y, b.z, b.w};
            float mm[4] = {m.x, m.y, m.z, m.w};
            float va[4] = {vv.x, vv.y, vv.z, vv.w};
            float rr[4] = {rs.x, rs.y, rs.z, rs.w};
            float4 res;
            float* rp = &res.x;
            #pragma unroll
            for (int j = 0; j < 4; ++j) {
                float v = 0.25f * o[j] + bb[j];
                float sg = gg[j] / sqrtf(va[j] + BNEPS);
                v = (v - mm[j]) * sg + be[j];
                v = v > 0.f ? v : __expf(v) - 1.f;
                rp[j] = v + rr[j];
            }
            *(float4*)(outp + (size_t)node * ldo + cin) = res;
        }
    }
}

// ---------- graph boundaries + pool-accumulator zeroing (fused) ----------
__global__ void gstart_kernel(const int* __restrict__ batch, int N, int* __restrict__ gstart,
                              float* __restrict__ hg_acc, float* __restrict__ wsum_acc)
{
    int t = threadIdx.x;   // 128 threads
    for (int idx = t; idx < NGRAPH * 64; idx += 128) hg_acc[idx] = 0.f;
    if (t < NGRAPH) wsum_acc[t] = 0.f;
    if (t <= NGRAPH) {
        int lo = 0, hi = N;
        while (lo < hi) {
            int mid = (lo + hi) >> 1;
            if (batch[mid] < t) lo = mid + 1; else hi = mid;
        }
        gstart[t] = lo;
    }
}

// ---------- pooling partial sums ----------
__global__ __launch_bounds__(256)
void pool_partial(const float* __restrict__ hjk, const float* __restrict__ w,
                  const int* __restrict__ batch, const int* __restrict__ gstart,
                  float* __restrict__ hg_acc, float* __restrict__ wsum_acc, int N)
{
    __shared__ float red[256];
    __shared__ float wred[4];
    int tid = threadIdx.x;
    int c = tid & 63, q = tid >> 6;
    int slab = (N + POOL_BLOCKS - 1) / POOL_BLOCKS;
    int n0 = blockIdx.x * slab;
    int n1 = n0 + slab; if (n1 > N) n1 = N;
    if (n0 >= n1) return;
    int g0 = batch[n0], g1 = batch[n1 - 1];

    for (int g = g0; g <= g1; ++g) {
        int s = gstart[g];     if (s < n0) s = n0;
        int e = gstart[g + 1]; if (e > n1) e = n1;
        float acc = 0.f, ws = 0.f;
        for (int n = s + q; n < e; n += 4) {
            float wn = w[n];
            acc += wn * hjk[(size_t)n * 64 + c];
            if (c == 0) ws += wn;
        }
        red[tid] = acc;
        if (c == 0) wred[q] = ws;
        __syncthreads();
        if (q == 0) {
            float v = red[c] + red[64 + c] + red[128 + c] + red[192 + c];
            if (v != 0.f) atomicAdd(&hg_acc[g * 64 + c], v);
            if (c == 0) {
                float t = wred[0] + wred[1] + wred[2] + wred[3];
                if (t != 0.f) atomicAdd(&wsum_acc[g], t);
            }
        }
        __syncthreads();
    }
}

// ---------- classifier head ----------
__global__ void cls_kernel(const float* __restrict__ hg_acc,
                           const float* __restrict__ wsum_acc,
                           const float* __restrict__ W1, const float* __restrict__ b1,
                           const float* __restrict__ W2, const float* __restrict__ b2,
                           float* __restrict__ out)
{
    int g = blockIdx.x, t = threadIdx.x;  // 32 threads
    __shared__ float z[32];
    __shared__ float h[64];
    float wsum = wsum_acc[g];
    float rw = (wsum > 0.f) ? 1.f / wsum : 0.f;
    h[t] = hg_acc[g * 64 + t] * rw;
    h[t + 32] = hg_acc[g * 64 + t + 32] * rw;
    __syncthreads();
    float acc = b1[t];
    for (int k = 0; k < 64; ++k) acc += h[k] * W1[k * 32 + t];
    z[t] = fmaxf(acc, 0.f);
    __syncthreads();
    if (t < 2) {
        float o = b2[t];
        for (int j = 0; j < 32; ++j) o += z[j] * W2[j * 2 + t];
        out[g * 2 + t] = o;
    }
}

extern "C" void kernel_launch(void* const* d_in, const int* in_sizes, int n_in,
                              void* d_out, int out_size, void* d_ws, size_t ws_size,
                              hipStream_t stream)
{
    const float* x        = (const float*)d_in[0];
    const int*   ei       = (const int*)d_in[1];
    const int*   batch    = (const int*)d_in[2];
    const float* conv0_W  = (const float*)d_in[3];
    const float* conv0_as = (const float*)d_in[4];
    const float* conv0_ad = (const float*)d_in[5];
    const float* conv0_b  = (const float*)d_in[6];
    const float* pre0_W   = (const float*)d_in[7];
    const float* pre0_b   = (const float*)d_in[8];
    const float* convs_W  = (const float*)d_in[9];
    const float* convs_as = (const float*)d_in[10];
    const float* convs_ad = (const float*)d_in[11];
    const float* convs_b  = (const float*)d_in[12];
    const float* bn_g     = (const float*)d_in[13];
    const float* bn_b     = (const float*)d_in[14];
    const float* bn_m     = (const float*)d_in[15];
    const float* bn_v     = (const float*)d_in[16];
    const float* jump_W   = (const float*)d_in[17];
    const float* jump_b   = (const float*)d_in[18];
    const float* att_W    = (const float*)d_in[19];
    const float* att_b    = (const float*)d_in[20];
    const float* cls_W1   = (const float*)d_in[21];
    const float* cls_b1   = (const float*)d_in[22];
    const float* cls_W2   = (const float*)d_in[23];
    const float* cls_b2   = (const float*)d_in[24];
    float* out = (float*)d_out;

    const int N = in_sizes[0] / 128;   // 50000
    const int E = in_sizes[1] / 2;     // 400000
    const int Etot = E + N;
    const int nb = (N + SCAN_CHUNK - 1) / SCAN_CHUNK;   // 25 <= 64

    // workspace layout
    float* ws      = (float*)d_ws;
    unsigned short* xh_bf   = (unsigned short*)ws;          // N*256 bf16
    unsigned short* h256_bf = xh_bf + (size_t)N * 256;      // N*256 bf16
    float* repsAll = (float*)(h256_bf + (size_t)N * 256);   // N*192 f32
    float* as_n    = repsAll + (size_t)N * 192;             // N*4
    float* ad_n    = as_n + (size_t)N * 4;                  // N*4
    float* hjk     = ad_n + (size_t)N * 4;                  // N*64
    float* hg_acc  = hjk + (size_t)N * 64;                  // 64*64
    float* wsum_acc= hg_acc + NGRAPH * 64;                  // 64
    int*   rowptr  = (int*)(wsum_acc + NGRAPH);             // N+1
    int*   cursor  = rowptr + (N + 1);                      // N
    int*   counts  = cursor + N;                            // N
    int*   csr_src = counts + N;                            // Etot
    int*   gstart  = csr_src + Etot;                        // 65
    int*   blocksum = gstart + (NGRAPH + 1);                // 64
    float* wbuf    = as_n;  // reuse (free after last layer)

    dim3 blk(256);
    int node_wave_blocks = (N + 3) / 4;
    int edge_blocks      = (Etot + 255) / 256;
    int row_blocks       = (N + 63) / 64;

    // ---------------- CSR build ----------------
    hipMemsetAsync(counts, 0, (size_t)N * sizeof(int), stream);
    hist_kernel<<<edge_blocks, blk, 0, stream>>>(ei, E, N, counts);
    scan_phase1<<<nb, blk, 0, stream>>>(counts, N, blocksum);
    scan_phase3<<<nb, blk, 0, stream>>>(counts, N, nb, blocksum, rowptr, cursor);
    scatter_kernel<<<edge_blocks, blk, 0, stream>>>(ei, E, N, cursor, csr_src);

    // ---------------- layer 0 ----------------
    {
        dim3 g1(row_blocks, 4);
        gemm_xh_mfma<<<g1, blk, 0, stream>>>(x, 128, conv0_W, 256, N, 128,
                                             conv0_as, conv0_ad, as_n, ad_n, xh_bf);
        aggregate_kernel<<<node_wave_blocks, blk, 0, stream>>>(
            rowptr, csr_src, as_n, ad_n, xh_bf, conv0_b, (float*)h256_bf, 256, N, 0,
            nullptr, nullptr, nullptr, nullptr, nullptr);
        gemm_n64_mfma<<<row_blocks, blk, 0, stream>>>(h256_bf, 256, 1, pre0_W, N, 256,
                                                      pre0_b, repsAll, 192, 1,
                                                      bn_g, bn_b, bn_m, bn_v,
                                                      nullptr, nullptr, nullptr);
    }

    // ---------------- layers 1, 2 ----------------
    for (int i = 0; i < 2; ++i) {
        dim3 g1(row_blocks, 4);
        gemm_xh_mfma<<<g1, blk, 0, stream>>>(repsAll + i * 64, 192,
                                             convs_W + (size_t)i * 64 * 256, 256, N, 64,
                                             convs_as + i * 256, convs_ad + i * 256,
                                             as_n, ad_n, xh_bf);
        aggregate_kernel<<<node_wave_blocks, blk, 0, stream>>>(
            rowptr, csr_src, as_n, ad_n, xh_bf, convs_b + i * 64,
            repsAll + (i + 1) * 64, 192, N, 1,
            bn_g + (i + 1) * 64, bn_b + (i + 1) * 64,
            bn_m + (i + 1) * 64, bn_v + (i + 1) * 64,
            repsAll + i * 64);
    }

    // ---------------- JK projection + fused pool logits ----------------
    gemm_n64_mfma<<<row_blocks, blk, 0, stream>>>(repsAll, 192, 0, jump_W, N, 192,
                                                  jump_b, hjk, 64, 0,
                                                  nullptr, nullptr, nullptr, nullptr,
                                                  att_W, att_b, wbuf);

    // ---------------- pooling + classifier ----------------
    gstart_kernel<<<1, 128, 0, stream>>>(batch, N, gstart, hg_acc, wsum_acc);
    pool_partial<<<POOL_BLOCKS, blk, 0, stream>>>(hjk, wbuf, batch, gstart,
                                                  hg_acc, wsum_acc, N);
    cls_kernel<<<NGRAPH, 32, 0, stream>>>(hg_acc, wsum_acc, cls_W1, cls_b1,
                                          cls_W2, cls_b2, out);
}

// Round 16
// 400.448 us; speedup vs baseline: 1.0467x; 1.0317x over previous
//
#include <hip/hip_runtime.h>
#include <hip/hip_bf16.h>
#include <math.h>

#define NEG 0.2f
#define BNEPS 1e-5f
#define NGRAPH 64
#define SCAN_CHUNK 2048
#define POOL_BLOCKS 256

typedef short bf16x8 __attribute__((ext_vector_type(8)));            // 8 bf16 (4 VGPRs)
typedef float f32x4  __attribute__((ext_vector_type(4)));            // MFMA accumulator

__device__ __forceinline__ float bf2f(unsigned short u) {
    return __uint_as_float(((unsigned)u) << 16);
}
__device__ __forceinline__ short f2bf(float f) {
    return (short)__bfloat16_as_ushort(__float2bfloat16(f));
}

// ---------- init: zero counts, zero pool accumulators, compute gstart ----------
__global__ __launch_bounds__(256)
void init_kernel(const int* __restrict__ batch, int N,
                 int* __restrict__ counts, int* __restrict__ gstart,
                 float* __restrict__ hg_acc, float* __restrict__ wsum_acc)
{
    int idx = blockIdx.x * 256 + threadIdx.x;
    for (int i = idx; i < N; i += gridDim.x * 256) counts[i] = 0;
    if (blockIdx.x == 0) {
        int t = threadIdx.x;
        for (int i = t; i < NGRAPH * 64; i += 256) hg_acc[i] = 0.f;
        if (t < NGRAPH) wsum_acc[t] = 0.f;
        if (t <= NGRAPH) {
            int lo = 0, hi = N;
            while (lo < hi) {
                int mid = (lo + hi) >> 1;
                if (batch[mid] < t) lo = mid + 1; else hi = mid;
            }
            gstart[t] = lo;
        }
    }
}

// ---------- MFMA bf16 GEMM for xh: Cbf[M,256] = bf16(A[M,K] @ W[K,256]) ----------
// + fused attention dots. grid (ceil(M/64), 4), block 256. head = blockIdx.y.
__global__ __launch_bounds__(256)
void gemm_xh_mfma(const float* __restrict__ A, int lda,
                  const float* __restrict__ W, int Nc, int M, int K,
                  const float* __restrict__ att_s, const float* __restrict__ att_d,
                  float* __restrict__ as_out, float* __restrict__ ad_out,
                  unsigned short* __restrict__ Cbf)
{
    __shared__ short Wt[64 * 136];           // max K=128 -> KP=136
    const int KP = K + 8;
    int tid  = threadIdx.x;
    int lane = tid & 63, wave = tid >> 6;
    int row0 = blockIdx.x * 64;
    int colb = blockIdx.y * 64;
    int c15 = lane & 15, q = lane >> 4;

    {
        int n = tid & 63;
        for (int k = tid >> 6; k < K; k += 4)
            Wt[n * KP + k] = f2bf(W[(size_t)k * Nc + colb + n]);
    }
    __syncthreads();

    int row = row0 + wave * 16 + c15;
    bool rok = row < M;
    const float* arow = A + (size_t)row * lda + q * 8;

    f32x4 acc[4];
    #pragma unroll
    for (int st = 0; st < 4; ++st) acc[st] = (f32x4){0.f, 0.f, 0.f, 0.f};

    for (int k0 = 0; k0 < K; k0 += 32) {
        bf16x8 av;
        if (rok) {
            float4 a0 = *(const float4*)(arow + k0);
            float4 a1 = *(const float4*)(arow + k0 + 4);
            av[0] = f2bf(a0.x); av[1] = f2bf(a0.y); av[2] = f2bf(a0.z); av[3] = f2bf(a0.w);
            av[4] = f2bf(a1.x); av[5] = f2bf(a1.y); av[6] = f2bf(a1.z); av[7] = f2bf(a1.w);
        } else {
            av = (bf16x8){0,0,0,0,0,0,0,0};
        }
        #pragma unroll
        for (int st = 0; st < 4; ++st) {
            bf16x8 bv = *(const bf16x8*)(Wt + (st * 16 + c15) * KP + k0 + q * 8);
            acc[st] = __builtin_amdgcn_mfma_f32_16x16x32_bf16(av, bv, acc[st], 0, 0, 0);
        }
    }

    #pragma unroll
    for (int r = 0; r < 4; ++r) {
        int orow = row0 + wave * 16 + q * 4 + r;
        if (orow >= M) continue;
        unsigned short* cb = Cbf + (size_t)orow * 256 + colb + c15;
        #pragma unroll
        for (int st = 0; st < 4; ++st)
            cb[st * 16] = (unsigned short)f2bf(acc[st][r]);
    }
    float sa[4], da[4];
    #pragma unroll
    for (int st = 0; st < 4; ++st) {
        sa[st] = att_s[colb + st * 16 + c15];
        da[st] = att_d[colb + st * 16 + c15];
    }
    #pragma unroll
    for (int r = 0; r < 4; ++r) {
        float ps = acc[0][r] * sa[0] + acc[1][r] * sa[1] + acc[2][r] * sa[2] + acc[3][r] * sa[3];
        float pd = acc[0][r] * da[0] + acc[1][r] * da[1] + acc[2][r] * da[2] + acc[3][r] * da[3];
        #pragma unroll
        for (int o = 1; o < 16; o <<= 1) {
            ps += __shfl_xor(ps, o);
            pd += __shfl_xor(pd, o);
        }
        int orow = row0 + wave * 16 + q * 4 + r;
        if (c15 == 0 && orow < M) {
            as_out[orow * 4 + blockIdx.y] = ps;
            ad_out[orow * 4 + blockIdx.y] = pd;
        }
    }
}

// ---------- MFMA bf16 GEMM, Nc=64 (pre0 / jump) + optional fused pool logits ----------
__global__ __launch_bounds__(256)
void gemm_n64_mfma(const void* __restrict__ Araw, int lda, int a_is_bf16,
                   const float* __restrict__ W, int M, int K,
                   const float* __restrict__ bias,
                   float* __restrict__ C, int ldc, int mode,
                   const float* __restrict__ bn_g, const float* __restrict__ bn_b,
                   const float* __restrict__ bn_m, const float* __restrict__ bn_v,
                   const float* __restrict__ attW, const float* __restrict__ attb,
                   float* __restrict__ wout)
{
    __shared__ short Wt[64 * 264];           // max K=256 -> KP=264
    const int KP = K + 8;
    int tid  = threadIdx.x;
    int lane = tid & 63, wave = tid >> 6;
    int row0 = blockIdx.x * 64;
    int c15 = lane & 15, q = lane >> 4;

    {
        int n = tid & 63;
        for (int k = tid >> 6; k < K; k += 4)
            Wt[n * KP + k] = f2bf(W[(size_t)k * 64 + n]);
    }
    __syncthreads();

    int row = row0 + wave * 16 + c15;
    bool rok = row < M;

    f32x4 acc[4];
    #pragma unroll
    for (int st = 0; st < 4; ++st) acc[st] = (f32x4){0.f, 0.f, 0.f, 0.f};

    for (int k0 = 0; k0 < K; k0 += 32) {
        bf16x8 av;
        if (rok) {
            if (a_is_bf16) {
                av = *(const bf16x8*)((const unsigned short*)Araw
                                      + (size_t)row * lda + k0 + q * 8);
            } else {
                const float* ap = (const float*)Araw + (size_t)row * lda + k0 + q * 8;
                float4 a0 = *(const float4*)ap;
                float4 a1 = *(const float4*)(ap + 4);
                av[0] = f2bf(a0.x); av[1] = f2bf(a0.y); av[2] = f2bf(a0.z); av[3] = f2bf(a0.w);
                av[4] = f2bf(a1.x); av[5] = f2bf(a1.y); av[6] = f2bf(a1.z); av[7] = f2bf(a1.w);
            }
        } else {
            av = (bf16x8){0,0,0,0,0,0,0,0};
        }
        #pragma unroll
        for (int st = 0; st < 4; ++st) {
            bf16x8 bv = *(const bf16x8*)(Wt + (st * 16 + c15) * KP + k0 + q * 8);
            acc[st] = __builtin_amdgcn_mfma_f32_16x16x32_bf16(av, bv, acc[st], 0, 0, 0);
        }
    }

    #pragma unroll
    for (int st = 0; st < 4; ++st) {
        int col = st * 16 + c15;
        float bs = bias ? bias[col] : 0.f;
        float sg = 1.f, sb = 0.f;
        if (mode == 1) {
            sg = bn_g[col] / sqrtf(bn_v[col] + BNEPS);
            sb = bn_b[col] - bn_m[col] * sg;
        }
        #pragma unroll
        for (int r = 0; r < 4; ++r) {
            int orow = row0 + wave * 16 + q * 4 + r;
            if (orow >= M) continue;
            float v = acc[st][r] + bs;
            if (mode == 1) {
                v = v * sg + sb;
                v = v > 0.f ? v : __expf(v) - 1.f;
            }
            acc[st][r] = v;
            C[(size_t)orow * ldc + col] = v;
        }
    }

    if (wout) {
        float sa[4];
        #pragma unroll
        for (int st = 0; st < 4; ++st) sa[st] = attW[st * 16 + c15];
        float ab = attb[0];
        #pragma unroll
        for (int r = 0; r < 4; ++r) {
            float ps = acc[0][r] * sa[0] + acc[1][r] * sa[1]
                     + acc[2][r] * sa[2] + acc[3][r] * sa[3];
            #pragma unroll
            for (int o = 1; o < 16; o <<= 1) ps += __shfl_xor(ps, o);
            int orow = row0 + wave * 16 + q * 4 + r;
            if (c15 == 0 && orow < M) wout[orow] = __expf(ps + ab);
        }
    }
}

// ---------- CSR build: histogram over dst ----------
__global__ __launch_bounds__(256)
void hist_kernel(const int* __restrict__ ei, int E, int N, int* __restrict__ counts)
{
    int e = blockIdx.x * blockDim.x + threadIdx.x;
    int Etot = E + N;
    if (e >= Etot) return;
    int d = (e < E) ? ei[E + e] : e - E;
    atomicAdd(&counts[d], 1);
}

// ---------- scan phase 1: per-block partial sums ----------
__global__ __launch_bounds__(256)
void scan_phase1(const int* __restrict__ counts, int N, int* __restrict__ blocksum)
{
    __shared__ int wsum[4];
    int tid = threadIdx.x, lane = tid & 63, wave = tid >> 6;
    int base = blockIdx.x * SCAN_CHUNK;
    int s = 0;
    #pragma unroll
    for (int j = 0; j < SCAN_CHUNK / 256; ++j) {
        int idx = base + tid + j * 256;
        if (idx < N) s += counts[idx];
    }
    #pragma unroll
    for (int o = 32; o; o >>= 1) s += __shfl_xor(s, o);
    if (lane == 0) wsum[wave] = s;
    __syncthreads();
    if (tid == 0) blocksum[blockIdx.x] = wsum[0] + wsum[1] + wsum[2] + wsum[3];
}

// ---------- scan phase 3 (merged with global prefix of block sums) ----------
__global__ __launch_bounds__(256)
void scan_phase3(const int* __restrict__ counts, int N, int nb,
                 const int* __restrict__ blocksum,
                 int* __restrict__ rowptr, int* __restrict__ cursor)
{
    __shared__ int wsum[4];
    __shared__ int pref[64];
    int tid = threadIdx.x, lane = tid & 63, wave = tid >> 6;

    if (wave == 0) {
        int v = (lane < nb) ? blocksum[lane] : 0;
        int incl = v;
        #pragma unroll
        for (int o = 1; o < 64; o <<= 1) {
            int t = __shfl_up(incl, o);
            if (lane >= o) incl += t;
        }
        pref[lane] = incl;
    }
    __syncthreads();
    int boff = blockIdx.x ? pref[blockIdx.x - 1] : 0;
    if (blockIdx.x == 0 && tid == 0) rowptr[N] = pref[nb - 1];

    int start = blockIdx.x * SCAN_CHUNK + tid * 8;
    int v[8];
    int s = 0;
    #pragma unroll
    for (int j = 0; j < 8; ++j) {
        v[j] = (start + j < N) ? counts[start + j] : 0;
        s += v[j];
    }
    int incl = s;
    #pragma unroll
    for (int o = 1; o < 64; o <<= 1) {
        int t = __shfl_up(incl, o);
        if (lane >= o) incl += t;
    }
    if (lane == 63) wsum[wave] = incl;
    __syncthreads();
    int woff = 0;
    #pragma unroll
    for (int w = 0; w < 4; ++w) if (w < wave) woff += wsum[w];
    int run = boff + woff + incl - s;
    #pragma unroll
    for (int j = 0; j < 8; ++j) {
        int idx = start + j;
        if (idx < N) { rowptr[idx] = run; cursor[idx] = run; }
        run += v[j];
    }
}

// ---------- CSR build: scatter ----------
__global__ __launch_bounds__(256)
void scatter_kernel(const int* __restrict__ ei, int E, int N,
                    int* __restrict__ cursor, int* __restrict__ csr_src)
{
    int e = blockIdx.x * blockDim.x + threadIdx.x;
    int Etot = E + N;
    if (e >= Etot) return;
    int s, d;
    if (e < E) { s = ei[e]; d = ei[E + e]; } else { s = d = e - E; }
    int pos = atomicAdd(&cursor[d], 1);
    csr_src[pos] = s;
}

// ---------- fused per-node GAT aggregation v4 (in-register shfl weights) ----------
__global__ __launch_bounds__(256)
void aggregate_kernel(const int* __restrict__ rowptr, const int* __restrict__ csr_src,
                      const float* __restrict__ as_n, const float* __restrict__ ad_n,
                      const unsigned short* __restrict__ xh,
                      const float* __restrict__ bias,
                      float* __restrict__ outp, int ldo,
                      int N, int mode,
                      const float* __restrict__ bn_g, const float* __restrict__ bn_b,
                      const float* __restrict__ bn_m, const float* __restrict__ bn_v,
                      const float* __restrict__ resid)
{
    int node = (blockIdx.x * blockDim.x + threadIdx.x) >> 6;
    int lane = threadIdx.x & 63;
    if (node >= N) return;
    int h = lane >> 4, li = lane & 15, grp = lane & 48;
    int e0 = rowptr[node], e1 = rowptr[node + 1];
    float adh = ad_n[node * 4 + h];
    const unsigned char* xb = (const unsigned char*)xh;
    unsigned laneoff = (unsigned)(lane * 8);

    float4 acc = make_float4(0.f, 0.f, 0.f, 0.f);
    float wsum = 0.f;

    for (int base = e0; base < e1; base += 16) {
        int cnt = e1 - base; if (cnt > 16) cnt = 16;
        int s = 0; float w = 0.f;
        if (li < cnt) {
            s = csr_src[base + li];
            float l = as_n[s * 4 + h] + adh;
            l = fmaxf(l, NEG * l);
            w = __expf(l);
        }
        int k = 0;
        for (; k + 3 < cnt; k += 4) {
            float w0 = __shfl(w, grp + k),     w1 = __shfl(w, grp + k + 1);
            float w2 = __shfl(w, grp + k + 2), w3 = __shfl(w, grp + k + 3);
            int s0 = __shfl(s, grp + k),       s1 = __shfl(s, grp + k + 1);
            int s2 = __shfl(s, grp + k + 2),   s3 = __shfl(s, grp + k + 3);
            ushort4 xv0 = *(const ushort4*)(xb + ((unsigned)s0 * 512u + laneoff));
            ushort4 xv1 = *(const ushort4*)(xb + ((unsigned)s1 * 512u + laneoff));
            ushort4 xv2 = *(const ushort4*)(xb + ((unsigned)s2 * 512u + laneoff));
            ushort4 xv3 = *(const ushort4*)(xb + ((unsigned)s3 * 512u + laneoff));
            acc.x += w0 * bf2f(xv0.x); acc.y += w0 * bf2f(xv0.y);
            acc.z += w0 * bf2f(xv0.z); acc.w += w0 * bf2f(xv0.w);
            acc.x += w1 * bf2f(xv1.x); acc.y += w1 * bf2f(xv1.y);
            acc.z += w1 * bf2f(xv1.z); acc.w += w1 * bf2f(xv1.w);
            acc.x += w2 * bf2f(xv2.x); acc.y += w2 * bf2f(xv2.y);
            acc.z += w2 * bf2f(xv2.z); acc.w += w2 * bf2f(xv2.w);
            acc.x += w3 * bf2f(xv3.x); acc.y += w3 * bf2f(xv3.y);
            acc.z += w3 * bf2f(xv3.z); acc.w += w3 * bf2f(xv3.w);
            wsum += (w0 + w1) + (w2 + w3);
        }
        for (; k < cnt; ++k) {
            float wk = __shfl(w, grp + k);
            int sk = __shfl(s, grp + k);
            ushort4 xv = *(const ushort4*)(xb + ((unsigned)sk * 512u + laneoff));
            acc.x += wk * bf2f(xv.x); acc.y += wk * bf2f(xv.y);
            acc.z += wk * bf2f(xv.z); acc.w += wk * bf2f(xv.w);
            wsum += wk;
        }
    }

    float rw = 1.f / wsum;
    acc.x *= rw; acc.y *= rw; acc.z *= rw; acc.w *= rw;

    if (mode == 0) {
        float4 bs = *(const float4*)(bias + lane * 4);
        ushort4 pk;
        pk.x = (unsigned short)f2bf(acc.x + bs.x);
        pk.y = (unsigned short)f2bf(acc.y + bs.y);
        pk.z = (unsigned short)f2bf(acc.z + bs.z);
        pk.w = (unsigned short)f2bf(acc.w + bs.w);
        *(ushort4*)((unsigned short*)outp + (size_t)node * 256 + lane * 4) = pk;
    } else {
        #pragma unroll
        for (int off = 16; off <= 32; off <<= 1) {
            acc.x += __shfl_xor(acc.x, off);
            acc.y += __shfl_xor(acc.y, off);
            acc.z += __shfl_xor(acc.z, off);
            acc.w += __shfl_xor(acc.w, off);
        }
        if (lane < 16) {
            int cin = lane * 4;
            float4 bs = *(const float4*)(bias + cin);
            float4 g = *(const float4*)(bn_g + cin);
            float4 b = *(const float4*)(bn_b + cin);
            float4 m = *(const float4*)(bn_m + cin);
            float4 vv = *(const float4*)(bn_v + cin);
            float4 rs = *(const float4*)(resid + (size_t)node * ldo + cin);
            float o[4] = {acc.x, acc.y, acc.z, acc.w};
            float bb[4] = {bs.x, bs.y, bs.z, bs.w};
            float gg[4] = {g.x, g.y, g.z, g.w};
            float be[4] = {b.x, b.y, b.z, b.w};
            float mm[4] = {m.x, m.y, m.z, m.w};
            float va[4] = {vv.x, vv.y, vv.z, vv.w};
            float rr[4] = {rs.x, rs.y, rs.z, rs.w};
            float4 res;
            float* rp = &res.x;
            #pragma unroll
            for (int j = 0; j < 4; ++j) {
                float v = 0.25f * o[j] + bb[j];
                float sg = gg[j] / sqrtf(va[j] + BNEPS);
                v = (v - mm[j]) * sg + be[j];
                v = v > 0.f ? v : __expf(v) - 1.f;
                rp[j] = v + rr[j];
            }
            *(float4*)(outp + (size_t)node * ldo + cin) = res;
        }
    }
}

// ---------- pooling partial sums ----------
__global__ __launch_bounds__(256)
void pool_partial(const float* __restrict__ hjk, const float* __restrict__ w,
                  const int* __restrict__ batch, const int* __restrict__ gstart,
                  float* __restrict__ hg_acc, float* __restrict__ wsum_acc, int N)
{
    __shared__ float red[256];
    __shared__ float wred[4];
    int tid = threadIdx.x;
    int c = tid & 63, q = tid >> 6;
    int slab = (N + POOL_BLOCKS - 1) / POOL_BLOCKS;
    int n0 = blockIdx.x * slab;
    int n1 = n0 + slab; if (n1 > N) n1 = N;
    if (n0 >= n1) return;
    int g0 = batch[n0], g1 = batch[n1 - 1];

    for (int g = g0; g <= g1; ++g) {
        int s = gstart[g];     if (s < n0) s = n0;
        int e = gstart[g + 1]; if (e > n1) e = n1;
        float acc = 0.f, ws = 0.f;
        for (int n = s + q; n < e; n += 4) {
            float wn = w[n];
            acc += wn * hjk[(size_t)n * 64 + c];
            if (c == 0) ws += wn;
        }
        red[tid] = acc;
        if (c == 0) wred[q] = ws;
        __syncthreads();
        if (q == 0) {
            float v = red[c] + red[64 + c] + red[128 + c] + red[192 + c];
            if (v != 0.f) atomicAdd(&hg_acc[g * 64 + c], v);
            if (c == 0) {
                float t = wred[0] + wred[1] + wred[2] + wred[3];
                if (t != 0.f) atomicAdd(&wsum_acc[g], t);
            }
        }
        __syncthreads();
    }
}

// ---------- classifier head ----------
__global__ void cls_kernel(const float* __restrict__ hg_acc,
                           const float* __restrict__ wsum_acc,
                           const float* __restrict__ W1, const float* __restrict__ b1,
                           const float* __restrict__ W2, const float* __restrict__ b2,
                           float* __restrict__ out)
{
    int g = blockIdx.x, t = threadIdx.x;  // 32 threads
    __shared__ float z[32];
    __shared__ float h[64];
    float wsum = wsum_acc[g];
    float rw = (wsum > 0.f) ? 1.f / wsum : 0.f;
    h[t] = hg_acc[g * 64 + t] * rw;
    h[t + 32] = hg_acc[g * 64 + t + 32] * rw;
    __syncthreads();
    float acc = b1[t];
    for (int k = 0; k < 64; ++k) acc += h[k] * W1[k * 32 + t];
    z[t] = fmaxf(acc, 0.f);
    __syncthreads();
    if (t < 2) {
        float o = b2[t];
        for (int j = 0; j < 32; ++j) o += z[j] * W2[j * 2 + t];
        out[g * 2 + t] = o;
    }
}

extern "C" void kernel_launch(void* const* d_in, const int* in_sizes, int n_in,
                              void* d_out, int out_size, void* d_ws, size_t ws_size,
                              hipStream_t stream)
{
    const float* x        = (const float*)d_in[0];
    const int*   ei       = (const int*)d_in[1];
    const int*   batch    = (const int*)d_in[2];
    const float* conv0_W  = (const float*)d_in[3];
    const float* conv0_as = (const float*)d_in[4];
    const float* conv0_ad = (const float*)d_in[5];
    const float* conv0_b  = (const float*)d_in[6];
    const float* pre0_W   = (const float*)d_in[7];
    const float* pre0_b   = (const float*)d_in[8];
    const float* convs_W  = (const float*)d_in[9];
    const float* convs_as = (const float*)d_in[10];
    const float* convs_ad = (const float*)d_in[11];
    const float* convs_b  = (const float*)d_in[12];
    const float* bn_g     = (const float*)d_in[13];
    const float* bn_b     = (const float*)d_in[14];
    const float* bn_m     = (const float*)d_in[15];
    const float* bn_v     = (const float*)d_in[16];
    const float* jump_W   = (const float*)d_in[17];
    const float* jump_b   = (const float*)d_in[18];
    const float* att_W    = (const float*)d_in[19];
    const float* att_b    = (const float*)d_in[20];
    const float* cls_W1   = (const float*)d_in[21];
    const float* cls_b1   = (const float*)d_in[22];
    const float* cls_W2   = (const float*)d_in[23];
    const float* cls_b2   = (const float*)d_in[24];
    float* out = (float*)d_out;

    const int N = in_sizes[0] / 128;   // 50000
    const int E = in_sizes[1] / 2;     // 400000
    const int Etot = E + N;
    const int nb = (N + SCAN_CHUNK - 1) / SCAN_CHUNK;   // 25 <= 64

    // workspace layout
    float* ws      = (float*)d_ws;
    unsigned short* xh_bf   = (unsigned short*)ws;          // N*256 bf16
    unsigned short* h256_bf = xh_bf + (size_t)N * 256;      // N*256 bf16
    float* repsAll = (float*)(h256_bf + (size_t)N * 256);   // N*192 f32
    float* as_n    = repsAll + (size_t)N * 192;             // N*4
    float* ad_n    = as_n + (size_t)N * 4;                  // N*4
    float* hjk     = ad_n + (size_t)N * 4;                  // N*64
    float* hg_acc  = hjk + (size_t)N * 64;                  // 64*64
    float* wsum_acc= hg_acc + NGRAPH * 64;                  // 64
    int*   rowptr  = (int*)(wsum_acc + NGRAPH);             // N+1
    int*   cursor  = rowptr + (N + 1);                      // N
    int*   counts  = cursor + N;                            // N
    int*   csr_src = counts + N;                            // Etot
    int*   gstart  = csr_src + Etot;                        // 65
    int*   blocksum = gstart + (NGRAPH + 1);                // 64
    float* wbuf    = as_n;  // reuse (free after last layer)

    dim3 blk(256);
    int node_wave_blocks = (N + 3) / 4;
    int edge_blocks      = (Etot + 255) / 256;
    int row_blocks       = (N + 63) / 64;

    // ---------------- init + CSR build ----------------
    init_kernel<<<64, blk, 0, stream>>>(batch, N, counts, gstart, hg_acc, wsum_acc);
    hist_kernel<<<edge_blocks, blk, 0, stream>>>(ei, E, N, counts);
    scan_phase1<<<nb, blk, 0, stream>>>(counts, N, blocksum);
    scan_phase3<<<nb, blk, 0, stream>>>(counts, N, nb, blocksum, rowptr, cursor);
    scatter_kernel<<<edge_blocks, blk, 0, stream>>>(ei, E, N, cursor, csr_src);

    // ---------------- layer 0 ----------------
    {
        dim3 g1(row_blocks, 4);
        gemm_xh_mfma<<<g1, blk, 0, stream>>>(x, 128, conv0_W, 256, N, 128,
                                             conv0_as, conv0_ad, as_n, ad_n, xh_bf);
        aggregate_kernel<<<node_wave_blocks, blk, 0, stream>>>(
            rowptr, csr_src, as_n, ad_n, xh_bf, conv0_b, (float*)h256_bf, 256, N, 0,
            nullptr, nullptr, nullptr, nullptr, nullptr);
        gemm_n64_mfma<<<row_blocks, blk, 0, stream>>>(h256_bf, 256, 1, pre0_W, N, 256,
                                                      pre0_b, repsAll, 192, 1,
                                                      bn_g, bn_b, bn_m, bn_v,
                                                      nullptr, nullptr, nullptr);
    }

    // ---------------- layers 1, 2 ----------------
    for (int i = 0; i < 2; ++i) {
        dim3 g1(row_blocks, 4);
        gemm_xh_mfma<<<g1, blk, 0, stream>>>(repsAll + i * 64, 192,
                                             convs_W + (size_t)i * 64 * 256, 256, N, 64,
                                             convs_as + i * 256, convs_ad + i * 256,
                                             as_n, ad_n, xh_bf);
        aggregate_kernel<<<node_wave_blocks, blk, 0, stream>>>(
            rowptr, csr_src, as_n, ad_n, xh_bf, convs_b + i * 64,
            repsAll + (i + 1) * 64, 192, N, 1,
            bn_g + (i + 1) * 64, bn_b + (i + 1) * 64,
            bn_m + (i + 1) * 64, bn_v + (i + 1) * 64,
            repsAll + i * 64);
    }

    // ---------------- JK projection + fused pool logits ----------------
    gemm_n64_mfma<<<row_blocks, blk, 0, stream>>>(repsAll, 192, 0, jump_W, N, 192,
                                                  jump_b, hjk, 64, 0,
                                                  nullptr, nullptr, nullptr, nullptr,
                                                  att_W, att_b, wbuf);

    // ---------------- pooling + classifier ----------------
    pool_partial<<<POOL_BLOCKS, blk, 0, stream>>>(hjk, wbuf, batch, gstart,
                                                  hg_acc, wsum_acc, N);
    cls_kernel<<<NGRAPH, 32, 0, stream>>>(hg_acc, wsum_acc, cls_W1, cls_b1,
                                          cls_W2, cls_b2, out);
}